// Round 7
// baseline (489.033 us; speedup 1.0000x reference)
//
#include <hip/hip_runtime.h>
#include <stdint.h>

#define NN 16384
#define FD 128

typedef float f32x4 __attribute__((ext_vector_type(4)));
typedef float f32x16 __attribute__((ext_vector_type(16)));
typedef __bf16 bf16x8 __attribute__((ext_vector_type(8)));
typedef unsigned short u16x8 __attribute__((ext_vector_type(8)));
typedef unsigned short u16x4 __attribute__((ext_vector_type(4)));

static __device__ __forceinline__ unsigned short f2bf(float x) {
  return __builtin_bit_cast(unsigned short, (__bf16)x);
}

static __device__ __forceinline__ u16x8 pack8(f32x4 a, f32x4 b) {
  u16x8 r;
  r[0] = f2bf(a.x); r[1] = f2bf(a.y); r[2] = f2bf(a.z); r[3] = f2bf(a.w);
  r[4] = f2bf(b.x); r[5] = f2bf(b.y); r[6] = f2bf(b.z); r[7] = f2bf(b.w);
  return r;
}

static __device__ __forceinline__ u16x4 pack4(f32x4 a) {
  u16x4 r;
  r[0] = f2bf(a.x); r[1] = f2bf(a.y); r[2] = f2bf(a.z); r[3] = f2bf(a.w);
  return r;
}

// async global->LDS, 16B per lane; LDS dest = wave-uniform base + lane*16
static __device__ __forceinline__ void gload_lds16(const void* g, void* l) {
  __builtin_amdgcn_global_load_lds(
      (const __attribute__((address_space(1))) unsigned int*)(uintptr_t)g,
      (__attribute__((address_space(3))) unsigned int*)(unsigned int)(uintptr_t)l,
      16, 0, 0);
}

// ============ PRIMARY PATH (needs ws >= 64KB + 4MB + 512MB) ============

// ---- kernel 1b: norm[i] = rsqrt(rowsum) AND bf16 pre-swizzled image of A ----
// 256 blocks x 1024 thr; block b owns rows [64b, 64b+64). Image layout = the
// exact swizzled LDS tile k3b wants: per step s (k-chunk of 256), 32 KB tile,
// byte (rloc*512 + kbyte) ^ ((rloc&15)<<4)  [XOR only touches bits 4-7].
__global__ __launch_bounds__(1024) void k_sumcast(
    const float* __restrict__ A, float* __restrict__ norm,
    unsigned short* __restrict__ img) {
  const int tid = threadIdx.x;
  const int b = blockIdx.x;
  const int i0 = b * 64;
  const int rloc = tid >> 4;
  const int l16 = tid & 15;
  const float* ar = A + (size_t)(i0 + rloc) * NN + (size_t)l16 * 4;
  char* ib = (char*)img + (size_t)b * 2097152 + (size_t)rloc * 512;
  const unsigned kxor = (unsigned)((rloc & 15) << 4);
  float sx = 0.f, sy = 0.f, sz = 0.f, sw = 0.f;
#pragma unroll 8
  for (int i = 0; i < 256; ++i) {
    f32x4 v = *(const f32x4*)(ar + (size_t)i * 64);
    sx += v.x; sy += v.y; sz += v.z; sw += v.w;
    const unsigned kb = (unsigned)(l16 * 8 + (i & 3) * 128) ^ kxor;
    __builtin_nontemporal_store(
        pack4(v), (u16x4*)(ib + (size_t)(i >> 2) * 32768 + kb));
  }
  float s = (sx + sy) + (sz + sw);
#pragma unroll
  for (int off = 8; off > 0; off >>= 1) s += __shfl_xor(s, off, 64);
  if (l16 == 0) norm[i0 + rloc] = s > 0.f ? 1.f / sqrtf(s) : 0.f;
}

// ---- kernel 3b: GEMM from the bf16 image (0.5 GiB A-read instead of 1 GiB) ----
// Staging = pure global_load_lds (linear dest, pre-swizzled source). m97 2-barrier
// dbuf loop. B-path / fragment math / epilogue identical to the R6 kernel.
__global__ __launch_bounds__(1024, 4) void k_gemm_img(
    const unsigned short* __restrict__ img,
    const unsigned short* __restrict__ Bfrag, const float* __restrict__ norm,
    const float* __restrict__ bias, float* __restrict__ out) {
  __shared__ __align__(16) unsigned short Alds[2][64 * 256];  // 2 x 32 KB

  const int tid = threadIdx.x;
  const int b = blockIdx.x;
  const int i0 = b * 64;

  const int wv = tid >> 6;          // 0..15
  const int c = wv & 3;             // col-group
  const int m = (wv >> 2) & 1;      // m-subtile
  const int kg = wv >> 3;           // k-half of BK=256
  const int l = tid & 63;
  const int lr = l & 31, lg = l >> 5;
  const int rowl = m * 32 + lr;
  const unsigned swz = (unsigned)((rowl & 15) << 4);
  const unsigned arb = (unsigned)(rowl * 512);
  const unsigned kgb = (unsigned)(kg * 256);

  const char* isrc = (const char*)img + (size_t)b * 2097152 +
                     (size_t)wv * 2048 + (size_t)l * 16;
  const char* bptr = (const char*)Bfrag + (size_t)(c * 64 + l) * 16 +
                     (size_t)kg * 8 * 4096;

  f32x16 acc;
#pragma unroll
  for (int i = 0; i < 16; ++i) acc[i] = 0.f;

#define STAGE(BUF, S)                                                       \
  {                                                                         \
    const char* s_ = isrc + (size_t)(S) * 32768;                            \
    char* d_ = (char*)Alds[BUF] + (size_t)wv * 2048 + (size_t)l * 16;       \
    gload_lds16(s_, d_);                                                    \
    gload_lds16(s_ + 1024, d_ + 1024);                                      \
  }
#define MFMA_BLOCK(CUR, S)                                                  \
  {                                                                         \
    const char* bp_ = bptr + (size_t)(S) * (16 * 4096);                     \
    _Pragma("unroll") for (int kf = 0; kf < 8; ++kf) {                      \
      u16x8 bv = *(const u16x8*)(bp_ + (size_t)kf * 4096);                  \
      unsigned ko = (kgb + (unsigned)(kf * 32) + (unsigned)(lg * 16)) ^ swz;\
      u16x8 av = *(const u16x8*)((const char*)Alds[CUR] + (arb + ko));      \
      acc = __builtin_amdgcn_mfma_f32_32x32x16_bf16(                        \
          __builtin_bit_cast(bf16x8, av), __builtin_bit_cast(bf16x8, bv),   \
          acc, 0, 0, 0);                                                    \
    }                                                                       \
  }

  STAGE(0, 0)
  __syncthreads();
#pragma unroll 1
  for (int s = 0; s < 64; ++s) {
    const int cur = s & 1;
    if (s + 1 < 64) STAGE(cur ^ 1, s + 1)
    MFMA_BLOCK(cur, s)
    __syncthreads();
  }
#undef MFMA_BLOCK
#undef STAGE

  // ---- epilogue: reduce kg halves via LDS, then coalesced store ----
  float* red = (float*)Alds;  // 64x128 f32 = 32 KB
  if (kg == 1) {
#pragma unroll
    for (int g = 0; g < 4; ++g) {
      const int jb = m * 32 + g * 8 + lg * 4;
#pragma unroll
      for (int r2 = 0; r2 < 4; ++r2)
        red[(jb + r2) * 128 + c * 32 + lr] = acc[g * 4 + r2];
    }
  }
  __syncthreads();
  if (kg == 0) {
#pragma unroll
    for (int g = 0; g < 4; ++g) {
      const int jb = m * 32 + g * 8 + lg * 4;
#pragma unroll
      for (int r2 = 0; r2 < 4; ++r2)
        red[(jb + r2) * 128 + c * 32 + lr] += acc[g * 4 + r2];
    }
  }
  __syncthreads();
  {
    const int row = tid >> 4;
    const int colseg = (tid & 15) * 8;
    const float nm = norm[i0 + row];
    f32x4 v0 = *(const f32x4*)(red + row * 128 + colseg);
    f32x4 v1 = *(const f32x4*)(red + row * 128 + colseg + 4);
    f32x4 b0v = *(const f32x4*)(bias + colseg);
    f32x4 b1v = *(const f32x4*)(bias + colseg + 4);
    f32x4 o0, o1;
    o0.x = nm * v0.x + b0v.x; o0.y = nm * v0.y + b0v.y;
    o0.z = nm * v0.z + b0v.z; o0.w = nm * v0.w + b0v.w;
    o1.x = nm * v1.x + b1v.x; o1.y = nm * v1.y + b1v.y;
    o1.z = nm * v1.z + b1v.z; o1.w = nm * v1.w + b1v.w;
    float* op = out + (size_t)(i0 + row) * FD + colseg;
    *(f32x4*)op = o0;
    *(f32x4*)(op + 4) = o1;
  }
}

// ------- kernel 2 (both paths): Bfrag = fragment-major bf16(norm[j]*(F@W^T)) -------
__global__ __launch_bounds__(256) void k_fwt(const float* __restrict__ F,
                                             const float* __restrict__ W,
                                             const float* __restrict__ norm,
                                             unsigned short* __restrict__ Bfrag) {
  const int tid = threadIdx.x;
  const int wv = tid >> 6;
  const int l = tid & 63;
  const int lr = l & 31, lg = l >> 5;
  const int j0 = blockIdx.x * 32;

  const float* fp = F + (size_t)(j0 + lr) * FD + lg * 8;
  const float* wp = W + (size_t)(wv * 32 + lr) * FD + lg * 8;

  f32x16 acc;
#pragma unroll
  for (int i = 0; i < 16; ++i) acc[i] = 0.f;

#pragma unroll
  for (int kf = 0; kf < 8; ++kf) {
    f32x4 fa = *(const f32x4*)(fp + kf * 16);
    f32x4 fb = *(const f32x4*)(fp + kf * 16 + 4);
    f32x4 wa = *(const f32x4*)(wp + kf * 16);
    f32x4 wb = *(const f32x4*)(wp + kf * 16 + 4);
    bf16x8 av = __builtin_bit_cast(bf16x8, pack8(fa, fb));
    bf16x8 bv = __builtin_bit_cast(bf16x8, pack8(wa, wb));
    acc = __builtin_amdgcn_mfma_f32_32x32x16_bf16(av, bv, acc, 0, 0, 0);
  }

  const int jt = blockIdx.x * 2;
#pragma unroll
  for (int g = 0; g < 4; ++g) {
    const int jb = j0 + g * 8 + lg * 4;
    u16x4 q;
#pragma unroll
    for (int r2 = 0; r2 < 4; ++r2) q[r2] = f2bf(acc[g * 4 + r2] * norm[jb + r2]);
    const size_t byteoff =
        ((size_t)((jt + (g >> 1)) * 4 + wv) * 64 + (g & 1) * 32 + lr) * 16 +
        lg * 8;
    *(u16x4*)((char*)Bfrag + byteoff) = q;
  }
}

// ============ FALLBACK PATH (small ws) — exact R6 kernels ============

__global__ __launch_bounds__(256) void k_rownorm(const float* __restrict__ A,
                                                 float* __restrict__ norm) {
  const int row = blockIdx.x;
  const f32x4* ar = (const f32x4*)(A + (size_t)row * NN);
  float s = 0.f;
#pragma unroll 4
  for (int c = threadIdx.x; c < NN / 4; c += 256) {
    f32x4 v = ar[c];
    s += (v.x + v.y) + (v.z + v.w);
  }
#pragma unroll
  for (int off = 32; off > 0; off >>= 1) s += __shfl_xor(s, off, 64);
  __shared__ float red[4];
  const int lane = threadIdx.x & 63, w = threadIdx.x >> 6;
  if (lane == 0) red[w] = s;
  __syncthreads();
  if (threadIdx.x == 0) {
    float d = (red[0] + red[1]) + (red[2] + red[3]);
    norm[row] = d > 0.f ? 1.f / sqrtf(d) : 0.f;
  }
}

__global__ __launch_bounds__(1024, 4) void k_gcn_gemm(
    const float* __restrict__ A, const unsigned short* __restrict__ Bfrag,
    const float* __restrict__ norm, const float* __restrict__ bias,
    float* __restrict__ out) {
  __shared__ __align__(16) unsigned short Alds[2][64 * 256];

  const int tid = threadIdx.x;
  const int i0 = blockIdx.x * 64;

  const int srow = tid >> 6;
  const int sl = tid & 63;
  const float* aptr = A + (size_t)(i0 + srow) * NN + (size_t)sl * 4;
  const unsigned abase =
      (unsigned)(srow * 512) + ((unsigned)(sl * 8) ^ (unsigned)(srow << 4));

  const int wv = tid >> 6;
  const int c = wv & 3;
  const int m = (wv >> 2) & 1;
  const int kg = wv >> 3;
  const int l = tid & 63;
  const int lr = l & 31, lg = l >> 5;
  const int rowl = m * 32 + lr;
  const unsigned swz = (unsigned)((rowl & 15) << 4);
  const unsigned arb = (unsigned)(rowl * 512);
  const unsigned kgb = (unsigned)(kg * 256);

  const char* bptr = (const char*)Bfrag + (size_t)(c * 64 + l) * 16 +
                     (size_t)kg * 8 * 4096;

  f32x16 acc;
#pragma unroll
  for (int i = 0; i < 16; ++i) acc[i] = 0.f;

  f32x4 a0, a1, a2, a3, b0, b1, b2, b3;

#define ALOAD(RV, S, I)                                                     \
  RV = __builtin_nontemporal_load(                                          \
      (const f32x4*)(aptr + (size_t)(S) * 256 + (size_t)(I) * (16 * NN)));
#define AWRITE(BUF, RV, I)                                                  \
  *(u16x4*)((char*)Alds[BUF] + (abase + (I) * 8192)) = pack4(RV);
#define BARR                                                                \
  do {                                                                      \
    asm volatile("s_waitcnt lgkmcnt(0)" ::: "memory");                      \
    __builtin_amdgcn_s_barrier();                                           \
    __builtin_amdgcn_sched_barrier(0);                                      \
  } while (0)
#define MFMA_BLOCK(CUR, S)                                                  \
  {                                                                         \
    const char* bp_ = bptr + (size_t)(S) * (16 * 4096);                     \
    _Pragma("unroll") for (int kf = 0; kf < 8; ++kf) {                      \
      u16x8 bv = *(const u16x8*)(bp_ + (size_t)kf * 4096);                  \
      unsigned ko = (kgb + (unsigned)(kf * 32) + (unsigned)(lg * 16)) ^ swz;\
      u16x8 av = *(const u16x8*)((const char*)Alds[CUR] + (arb + ko));      \
      acc = __builtin_amdgcn_mfma_f32_32x32x16_bf16(                        \
          __builtin_bit_cast(bf16x8, av), __builtin_bit_cast(bf16x8, bv),   \
          acc, 0, 0, 0);                                                    \
    }                                                                       \
  }

  ALOAD(a0, 0, 0) ALOAD(a1, 0, 1) ALOAD(a2, 0, 2) ALOAD(a3, 0, 3)
  ALOAD(b0, 1, 0) ALOAD(b1, 1, 1) ALOAD(b2, 1, 2) ALOAD(b3, 1, 3)
  AWRITE(0, a0, 0) AWRITE(0, a1, 1) AWRITE(0, a2, 2) AWRITE(0, a3, 3)
  BARR;

#pragma unroll 1
  for (int s = 0; s < 64; s += 2) {
    {
      if (s + 2 < 64) {
        ALOAD(a0, s + 2, 0) ALOAD(a1, s + 2, 1)
        ALOAD(a2, s + 2, 2) ALOAD(a3, s + 2, 3)
      }
      MFMA_BLOCK(0, s)
      AWRITE(1, b0, 0) AWRITE(1, b1, 1) AWRITE(1, b2, 2) AWRITE(1, b3, 3)
      BARR;
    }
    {
      if (s + 3 < 64) {
        ALOAD(b0, s + 3, 0) ALOAD(b1, s + 3, 1)
        ALOAD(b2, s + 3, 2) ALOAD(b3, s + 3, 3)
      }
      MFMA_BLOCK(1, s + 1)
      if (s + 2 < 64) {
        AWRITE(0, a0, 0) AWRITE(0, a1, 1) AWRITE(0, a2, 2) AWRITE(0, a3, 3)
      }
      BARR;
    }
  }
#undef MFMA_BLOCK
#undef BARR
#undef ALOAD
#undef AWRITE

  float* red = (float*)Alds;
  if (kg == 1) {
#pragma unroll
    for (int g = 0; g < 4; ++g) {
      const int jb = m * 32 + g * 8 + lg * 4;
#pragma unroll
      for (int r2 = 0; r2 < 4; ++r2)
        red[(jb + r2) * 128 + c * 32 + lr] = acc[g * 4 + r2];
    }
  }
  __syncthreads();
  if (kg == 0) {
#pragma unroll
    for (int g = 0; g < 4; ++g) {
      const int jb = m * 32 + g * 8 + lg * 4;
#pragma unroll
      for (int r2 = 0; r2 < 4; ++r2)
        red[(jb + r2) * 128 + c * 32 + lr] += acc[g * 4 + r2];
    }
  }
  __syncthreads();
  {
    const int row = tid >> 4;
    const int colseg = (tid & 15) * 8;
    const float nm = norm[i0 + row];
    f32x4 v0 = *(const f32x4*)(red + row * 128 + colseg);
    f32x4 v1 = *(const f32x4*)(red + row * 128 + colseg + 4);
    f32x4 b0v = *(const f32x4*)(bias + colseg);
    f32x4 b1v = *(const f32x4*)(bias + colseg + 4);
    f32x4 o0, o1;
    o0.x = nm * v0.x + b0v.x; o0.y = nm * v0.y + b0v.y;
    o0.z = nm * v0.z + b0v.z; o0.w = nm * v0.w + b0v.w;
    o1.x = nm * v1.x + b1v.x; o1.y = nm * v1.y + b1v.y;
    o1.z = nm * v1.z + b1v.z; o1.w = nm * v1.w + b1v.w;
    float* op = out + (size_t)(i0 + row) * FD + colseg;
    *(f32x4*)op = o0;
    *(f32x4*)(op + 4) = o1;
  }
}

extern "C" void kernel_launch(void* const* d_in, const int* in_sizes, int n_in,
                              void* d_out, int out_size, void* d_ws,
                              size_t ws_size, hipStream_t stream) {
  (void)in_sizes; (void)n_in; (void)out_size;
  const float* A = (const float*)d_in[0];
  const float* F = (const float*)d_in[1];
  const float* W = (const float*)d_in[2];
  const float* b = (const float*)d_in[3];
  float* out = (float*)d_out;

  float* norm = (float*)d_ws;                                     // 64 KB
  unsigned short* Bfrag = (unsigned short*)((char*)d_ws + 65536); // 4 MB

  const size_t need = 65536ULL + 4194304ULL + (size_t)NN * NN * 2ULL;
  if (ws_size >= need) {
    unsigned short* img = (unsigned short*)((char*)d_ws + 65536 + 4194304);
    k_sumcast<<<NN / 64, 1024, 0, stream>>>(A, norm, img);
    k_fwt<<<NN / 32, 256, 0, stream>>>(F, W, norm, Bfrag);
    k_gemm_img<<<NN / 64, 1024, 0, stream>>>(img, Bfrag, norm, b, out);
  } else {
    k_rownorm<<<NN, 256, 0, stream>>>(A, norm);
    k_fwt<<<NN / 32, 256, 0, stream>>>(F, W, norm, Bfrag);
    k_gcn_gemm<<<NN / 64, 1024, 0, stream>>>(A, Bfrag, norm, b, out);
  }
}

// Round 8
// 416.565 us; speedup vs baseline: 1.1740x; 1.1740x over previous
//
#include <hip/hip_runtime.h>
#include <stdint.h>

#define NN 16384
#define FD 128

typedef float f32x4 __attribute__((ext_vector_type(4)));
typedef float f32x16 __attribute__((ext_vector_type(16)));
typedef __bf16 bf16x8 __attribute__((ext_vector_type(8)));
typedef unsigned short u16x8 __attribute__((ext_vector_type(8)));
typedef unsigned short u16x4 __attribute__((ext_vector_type(4)));

static __device__ __forceinline__ unsigned short f2bf(float x) {
  return __builtin_bit_cast(unsigned short, (__bf16)x);
}

static __device__ __forceinline__ u16x8 pack8(f32x4 a, f32x4 b) {
  u16x8 r;
  r[0] = f2bf(a.x); r[1] = f2bf(a.y); r[2] = f2bf(a.z); r[3] = f2bf(a.w);
  r[4] = f2bf(b.x); r[5] = f2bf(b.y); r[6] = f2bf(b.z); r[7] = f2bf(b.w);
  return r;
}

static __device__ __forceinline__ u16x4 pack4(f32x4 a) {
  u16x4 r;
  r[0] = f2bf(a.x); r[1] = f2bf(a.y); r[2] = f2bf(a.z); r[3] = f2bf(a.w);
  return r;
}

// ---------------- kernel 1: norm[i] = (sum_j A[i][j])^-1/2 ----------------
// Plain cached loads: at k1's end the LAST ~256MB of A (high rows) sits in LLC;
// k3 consumes rows in REVERSE order to harvest those hits.
__global__ __launch_bounds__(256) void k_rownorm(const float* __restrict__ A,
                                                 float* __restrict__ norm) {
  const int row = blockIdx.x;
  const f32x4* ar = (const f32x4*)(A + (size_t)row * NN);
  float s = 0.f;
#pragma unroll 4
  for (int c = threadIdx.x; c < NN / 4; c += 256) {
    f32x4 v = ar[c];
    s += (v.x + v.y) + (v.z + v.w);
  }
#pragma unroll
  for (int off = 32; off > 0; off >>= 1) s += __shfl_xor(s, off, 64);
  __shared__ float red[4];
  const int lane = threadIdx.x & 63, w = threadIdx.x >> 6;
  if (lane == 0) red[w] = s;
  __syncthreads();
  if (threadIdx.x == 0) {
    float d = (red[0] + red[1]) + (red[2] + red[3]);
    norm[row] = d > 0.f ? 1.f / sqrtf(d) : 0.f;
  }
}

// ------- kernel 2: Bfrag = fragment-major bf16( norm[j] * (F @ W^T)[j][o] ) -------
// Bfrag layout: entry (t = j>>4, c = o>>5, lane l, e) at byte ((t*4+c)*64 + l)*16 + e*2
// holds norm[j]*H[j][o] with o = c*32 + (l&31), j = t*16 + (l>>5)*8 + e.
__global__ __launch_bounds__(256) void k_fwt(const float* __restrict__ F,
                                             const float* __restrict__ W,
                                             const float* __restrict__ norm,
                                             unsigned short* __restrict__ Bfrag) {
  const int tid = threadIdx.x;
  const int wv = tid >> 6;
  const int l = tid & 63;
  const int lr = l & 31, lg = l >> 5;
  const int j0 = blockIdx.x * 32;

  const float* fp = F + (size_t)(j0 + lr) * FD + lg * 8;
  const float* wp = W + (size_t)(wv * 32 + lr) * FD + lg * 8;

  f32x16 acc;
#pragma unroll
  for (int i = 0; i < 16; ++i) acc[i] = 0.f;

#pragma unroll
  for (int kf = 0; kf < 8; ++kf) {
    f32x4 fa = *(const f32x4*)(fp + kf * 16);
    f32x4 fb = *(const f32x4*)(fp + kf * 16 + 4);
    f32x4 wa = *(const f32x4*)(wp + kf * 16);
    f32x4 wb = *(const f32x4*)(wp + kf * 16 + 4);
    bf16x8 av = __builtin_bit_cast(bf16x8, pack8(fa, fb));
    bf16x8 bv = __builtin_bit_cast(bf16x8, pack8(wa, wb));
    acc = __builtin_amdgcn_mfma_f32_32x32x16_bf16(av, bv, acc, 0, 0, 0);
  }

  const int jt = blockIdx.x * 2;  // j0 >> 4
#pragma unroll
  for (int g = 0; g < 4; ++g) {
    const int jb = j0 + g * 8 + lg * 4;
    u16x4 q;
#pragma unroll
    for (int r2 = 0; r2 < 4; ++r2) q[r2] = f2bf(acc[g * 4 + r2] * norm[jb + r2]);
    const size_t byteoff =
        ((size_t)((jt + (g >> 1)) * 4 + wv) * 64 + (g & 1) * 32 + lr) * 16 +
        lg * 8;
    *(u16x4*)((char*)Bfrag + byteoff) = q;
  }
}

// ---------- kernel 3: out[i][o] = norm[i] * sum_j A[i][j]*(norm[j]*H[j][o]) + b[o] ----------
// R5 structure (best known). Changes vs R5: (1) blocks process row-tiles in
// REVERSE order so the A-tail still LLC-resident from k1 is read first;
// (2) A loads are plain (cached) so those LLC hits actually count.
// BM=64, BK=256. 256 blocks x 1024 thr (16 waves = 4 col x 2 m-sub x 2 k-groups).
// A: per-instruction wave-contiguous full-line loads -> regs -> bf16 -> swizzled
// LDS (2 x 32 KB dbuf). B: fragment-major bf16, coalesced 1KB/wave dwordx4 -> regs.
// K-split (kg) reduced via LDS in epilogue; coalesced f32x4 out stores.
__global__ __launch_bounds__(1024, 4) void k_gcn_gemm(
    const float* __restrict__ A, const unsigned short* __restrict__ Bfrag,
    const float* __restrict__ norm, const float* __restrict__ bias,
    float* __restrict__ out) {
  __shared__ __align__(16) unsigned short Alds[2][64 * 256];  // 2 x 32 KB

  const int tid = threadIdx.x;
  const int i0 = (int)(gridDim.x - 1 - blockIdx.x) * 64;  // reverse row order

  // A staging: wave w = srow, lane sl; load i covers row i*16+srow
  const int srow = tid >> 6;   // 0..15
  const int sl = tid & 63;
  const float* aptr = A + (size_t)(i0 + srow) * NN + (size_t)sl * 4;
  const unsigned abase =
      (unsigned)(srow * 512) + ((unsigned)(sl * 8) ^ (unsigned)(srow << 4));

  // fragment addressing
  const int wv = tid >> 6;          // 0..15
  const int c = wv & 3;             // col-group: o in [c*32, c*32+32)
  const int m = (wv >> 2) & 1;      // m-subtile: rows m*32..m*32+31
  const int kg = wv >> 3;           // k-half within BK=256
  const int l = tid & 63;
  const int lr = l & 31, lg = l >> 5;
  const int rowl = m * 32 + lr;
  const unsigned swz = (unsigned)((rowl & 15) << 4);
  const unsigned arb = (unsigned)(rowl * 512);
  const unsigned kgb = (unsigned)(kg * 256);  // kg*128 elements, bytes

  const char* bptr = (const char*)Bfrag + (size_t)(c * 64 + l) * 16 +
                     (size_t)kg * 8 * 4096;

  f32x16 acc;
#pragma unroll
  for (int i = 0; i < 16; ++i) acc[i] = 0.f;

#define ALOAD(RV, S, I)                                                     \
  RV = *(const f32x4*)(aptr + (size_t)(S) * 256 + (size_t)(I) * (16 * NN));
#define AWRITE(BUF, RV, I)                                                  \
  *(u16x4*)((char*)Alds[BUF] + (abase + (I) * 8192)) = pack4(RV);

  // prologue: stage tile 0 into buffer 0
  {
    f32x4 r0, r1, r2, r3;
    ALOAD(r0, 0, 0) ALOAD(r1, 0, 1) ALOAD(r2, 0, 2) ALOAD(r3, 0, 3)
    AWRITE(0, r0, 0) AWRITE(0, r1, 1) AWRITE(0, r2, 2) AWRITE(0, r3, 3)
  }
  __syncthreads();

#define GSTEP(CUR, NXT, S)                                                  \
  {                                                                         \
    const int s_ = (S);                                                     \
    const bool pf_ = (s_ + 1) < 64;                                         \
    f32x4 r0 = {}, r1 = {}, r2 = {}, r3 = {};                               \
    if (pf_) {                                                              \
      ALOAD(r0, s_ + 1, 0) ALOAD(r1, s_ + 1, 1)                             \
      ALOAD(r2, s_ + 1, 2) ALOAD(r3, s_ + 1, 3)                             \
    }                                                                       \
    const char* bp_ = bptr + (size_t)s_ * (16 * 4096);                      \
    _Pragma("unroll") for (int kf = 0; kf < 8; ++kf) {                      \
      u16x8 bv = *(const u16x8*)(bp_ + (size_t)kf * 4096);                  \
      unsigned ko = (kgb + (unsigned)(kf * 32) + (unsigned)(lg * 16)) ^ swz;\
      u16x8 av = *(const u16x8*)((const char*)Alds[CUR] + (arb + ko));      \
      acc = __builtin_amdgcn_mfma_f32_32x32x16_bf16(                        \
          __builtin_bit_cast(bf16x8, av), __builtin_bit_cast(bf16x8, bv),   \
          acc, 0, 0, 0);                                                    \
    }                                                                       \
    if (pf_) {                                                              \
      AWRITE(NXT, r0, 0) AWRITE(NXT, r1, 1)                                 \
      AWRITE(NXT, r2, 2) AWRITE(NXT, r3, 3)                                 \
    }                                                                       \
    __syncthreads();                                                        \
  }

#pragma unroll 1
  for (int s = 0; s < 64; s += 2) {
    GSTEP(0, 1, s)
    GSTEP(1, 0, s + 1)
  }
#undef GSTEP
#undef ALOAD
#undef AWRITE

  // ---- epilogue: reduce kg halves via LDS, then coalesced store ----
  // D: col(o-local) = c*32 + lr, row(i-local) = m*32 + g*8 + lg*4 + r2
  float* red = (float*)Alds;  // 64x128 f32 = 32 KB (final loop barrier passed)
  if (kg == 1) {
#pragma unroll
    for (int g = 0; g < 4; ++g) {
      const int jb = m * 32 + g * 8 + lg * 4;
#pragma unroll
      for (int r2 = 0; r2 < 4; ++r2)
        red[(jb + r2) * 128 + c * 32 + lr] = acc[g * 4 + r2];
    }
  }
  __syncthreads();
  if (kg == 0) {
#pragma unroll
    for (int g = 0; g < 4; ++g) {
      const int jb = m * 32 + g * 8 + lg * 4;
#pragma unroll
      for (int r2 = 0; r2 < 4; ++r2)
        red[(jb + r2) * 128 + c * 32 + lr] += acc[g * 4 + r2];
    }
  }
  __syncthreads();

  {
    const int row = tid >> 4;            // 0..63
    const int colseg = (tid & 15) * 8;   // 0..120
    const float nm = norm[i0 + row];
    f32x4 v0 = *(const f32x4*)(red + row * 128 + colseg);
    f32x4 v1 = *(const f32x4*)(red + row * 128 + colseg + 4);
    f32x4 b0v = *(const f32x4*)(bias + colseg);
    f32x4 b1v = *(const f32x4*)(bias + colseg + 4);
    f32x4 o0, o1;
    o0.x = nm * v0.x + b0v.x; o0.y = nm * v0.y + b0v.y;
    o0.z = nm * v0.z + b0v.z; o0.w = nm * v0.w + b0v.w;
    o1.x = nm * v1.x + b1v.x; o1.y = nm * v1.y + b1v.y;
    o1.z = nm * v1.z + b1v.z; o1.w = nm * v1.w + b1v.w;
    float* op = out + (size_t)(i0 + row) * FD + colseg;
    *(f32x4*)op = o0;
    *(f32x4*)(op + 4) = o1;
  }
}

extern "C" void kernel_launch(void* const* d_in, const int* in_sizes, int n_in,
                              void* d_out, int out_size, void* d_ws,
                              size_t ws_size, hipStream_t stream) {
  (void)in_sizes; (void)n_in; (void)out_size; (void)ws_size;
  const float* A = (const float*)d_in[0];
  const float* F = (const float*)d_in[1];
  const float* W = (const float*)d_in[2];
  const float* b = (const float*)d_in[3];
  float* out = (float*)d_out;

  float* norm = (float*)d_ws;                                     // 64 KB
  unsigned short* Bfrag = (unsigned short*)((char*)d_ws + 65536); // 4 MB

  k_rownorm<<<NN, 256, 0, stream>>>(A, norm);
  k_fwt<<<NN / 32, 256, 0, stream>>>(F, W, norm, Bfrag);
  k_gcn_gemm<<<NN / 64, 1024, 0, stream>>>(A, Bfrag, norm, b, out);
}

// Round 9
// 389.220 us; speedup vs baseline: 1.2564x; 1.0703x over previous
//
#include <hip/hip_runtime.h>
#include <stdint.h>

#define NN 16384
#define FD 128

typedef float f32x4 __attribute__((ext_vector_type(4)));
typedef float f32x16 __attribute__((ext_vector_type(16)));
typedef __bf16 bf16x8 __attribute__((ext_vector_type(8)));
typedef unsigned short u16x8 __attribute__((ext_vector_type(8)));
typedef unsigned short u16x4 __attribute__((ext_vector_type(4)));

static __device__ __forceinline__ unsigned short f2bf(float x) {
  return __builtin_bit_cast(unsigned short, (__bf16)x);
}

static __device__ __forceinline__ u16x8 pack8(f32x4 a, f32x4 b) {
  u16x8 r;
  r[0] = f2bf(a.x); r[1] = f2bf(a.y); r[2] = f2bf(a.z); r[3] = f2bf(a.w);
  r[4] = f2bf(b.x); r[5] = f2bf(b.y); r[6] = f2bf(b.z); r[7] = f2bf(b.w);
  return r;
}

static __device__ __forceinline__ u16x4 pack4(f32x4 a) {
  u16x4 r;
  r[0] = f2bf(a.x); r[1] = f2bf(a.y); r[2] = f2bf(a.z); r[3] = f2bf(a.w);
  return r;
}

// ---------------- kernel 1: norm[i] = (sum_j A[i][j])^-1/2 ----------------
// (R5-exact: nt loads)
__global__ __launch_bounds__(256) void k_rownorm(const float* __restrict__ A,
                                                 float* __restrict__ norm) {
  const int row = blockIdx.x;
  const f32x4* ar = (const f32x4*)(A + (size_t)row * NN);
  float s = 0.f;
#pragma unroll 4
  for (int c = threadIdx.x; c < NN / 4; c += 256) {
    f32x4 v = __builtin_nontemporal_load(&ar[c]);
    s += (v.x + v.y) + (v.z + v.w);
  }
#pragma unroll
  for (int off = 32; off > 0; off >>= 1) s += __shfl_xor(s, off, 64);
  __shared__ float red[4];
  const int lane = threadIdx.x & 63, w = threadIdx.x >> 6;
  if (lane == 0) red[w] = s;
  __syncthreads();
  if (threadIdx.x == 0) {
    float d = (red[0] + red[1]) + (red[2] + red[3]);
    norm[row] = d > 0.f ? 1.f / sqrtf(d) : 0.f;
  }
}

// ------- kernel 2: Bfrag = fragment-major bf16( norm[j] * (F @ W^T)[j][o] ) -------
// Bfrag layout: entry (t = j>>4, c = o>>5, lane l, e) at byte ((t*4+c)*64 + l)*16 + e*2
// holds norm[j]*H[j][o] with o = c*32 + (l&31), j = t*16 + (l>>5)*8 + e.
__global__ __launch_bounds__(256) void k_fwt(const float* __restrict__ F,
                                             const float* __restrict__ W,
                                             const float* __restrict__ norm,
                                             unsigned short* __restrict__ Bfrag) {
  const int tid = threadIdx.x;
  const int wv = tid >> 6;
  const int l = tid & 63;
  const int lr = l & 31, lg = l >> 5;
  const int j0 = blockIdx.x * 32;

  const float* fp = F + (size_t)(j0 + lr) * FD + lg * 8;
  const float* wp = W + (size_t)(wv * 32 + lr) * FD + lg * 8;

  f32x16 acc;
#pragma unroll
  for (int i = 0; i < 16; ++i) acc[i] = 0.f;

#pragma unroll
  for (int kf = 0; kf < 8; ++kf) {
    f32x4 fa = *(const f32x4*)(fp + kf * 16);
    f32x4 fb = *(const f32x4*)(fp + kf * 16 + 4);
    f32x4 wa = *(const f32x4*)(wp + kf * 16);
    f32x4 wb = *(const f32x4*)(wp + kf * 16 + 4);
    bf16x8 av = __builtin_bit_cast(bf16x8, pack8(fa, fb));
    bf16x8 bv = __builtin_bit_cast(bf16x8, pack8(wa, wb));
    acc = __builtin_amdgcn_mfma_f32_32x32x16_bf16(av, bv, acc, 0, 0, 0);
  }

  const int jt = blockIdx.x * 2;  // j0 >> 4
#pragma unroll
  for (int g = 0; g < 4; ++g) {
    const int jb = j0 + g * 8 + lg * 4;
    u16x4 q;
#pragma unroll
    for (int r2 = 0; r2 < 4; ++r2) q[r2] = f2bf(acc[g * 4 + r2] * norm[jb + r2]);
    const size_t byteoff =
        ((size_t)((jt + (g >> 1)) * 4 + wv) * 64 + (g & 1) * 32 + lr) * 16 +
        lg * 8;
    *(u16x4*)((char*)Bfrag + byteoff) = q;
  }
}

// ---------- kernel 3: out[i][o] = norm[i] * sum_j A[i][j]*(norm[j]*H[j][o]) + b[o] ----------
// R5 structure; single change: BM=32 -> 512 blocks x 512 thr = 2 blocks/CU so one
// block's MFMA phase covers the other's barrier drain (m114 wave-level overlap).
// 8 waves = 4 col-groups x 2 k-groups. LDS 2 x 16 KB dbuf.
// A: per-instruction wave-contiguous full-line nt loads -> regs -> bf16 -> swizzled LDS.
// B: fragment-major bf16, coalesced 1KB/wave dwordx4 -> regs.
// K-split (kg) reduced via LDS in epilogue; coalesced f32x4 out stores.
__global__ __launch_bounds__(512, 4) void k_gcn_gemm(
    const float* __restrict__ A, const unsigned short* __restrict__ Bfrag,
    const float* __restrict__ norm, const float* __restrict__ bias,
    float* __restrict__ out) {
  __shared__ __align__(16) unsigned short Alds[2][32 * 256];  // 2 x 16 KB

  const int tid = threadIdx.x;
  const int i0 = blockIdx.x * 32;

  // A staging: wave srow (0..7), lane sl; load I covers row I*8+srow
  const int srow = tid >> 6;
  const int sl = tid & 63;
  const float* aptr = A + (size_t)(i0 + srow) * NN + (size_t)sl * 4;
  // write byte for load I: (I*8+srow)*512 + (sl*8 ^ (((I*8+srow)&15)<<4))
  const unsigned ax0 = (unsigned)(sl * 8) ^ (unsigned)(srow << 4);
  const unsigned ax1 = (unsigned)(sl * 8) ^ (unsigned)((8 + srow) << 4);

  // fragment addressing
  const int wv = tid >> 6;          // 0..7
  const int c = wv & 3;             // col-group: o in [c*32, c*32+32)
  const int kg = wv >> 2;           // k-half within BK=256
  const int l = tid & 63;
  const int lr = l & 31, lg = l >> 5;
  const unsigned swz = (unsigned)((lr & 15) << 4);
  const unsigned arb = (unsigned)(lr * 512);
  const unsigned kgb = (unsigned)(kg * 256);  // kg*128 elements, bytes

  const char* bptr = (const char*)Bfrag + (size_t)(c * 64 + l) * 16 +
                     (size_t)kg * 8 * 4096;

  f32x16 acc;
#pragma unroll
  for (int i = 0; i < 16; ++i) acc[i] = 0.f;

#define ALOAD(RV, S, I)                                                     \
  RV = __builtin_nontemporal_load(                                          \
      (const f32x4*)(aptr + (size_t)(S) * 256 + (size_t)(I) * (8 * NN)));
#define AWRITE(BUF, RV, I)                                                  \
  *(u16x4*)((char*)Alds[BUF] +                                              \
            (((I) * 8 + srow) * 512 + (((I) & 1) ? ax1 : ax0))) = pack4(RV);

  // prologue: stage tile 0 into buffer 0
  {
    f32x4 r0, r1, r2, r3;
    ALOAD(r0, 0, 0) ALOAD(r1, 0, 1) ALOAD(r2, 0, 2) ALOAD(r3, 0, 3)
    AWRITE(0, r0, 0) AWRITE(0, r1, 1) AWRITE(0, r2, 2) AWRITE(0, r3, 3)
  }
  __syncthreads();

#define GSTEP(CUR, NXT, S)                                                  \
  {                                                                         \
    const int s_ = (S);                                                     \
    const bool pf_ = (s_ + 1) < 64;                                         \
    f32x4 r0 = {}, r1 = {}, r2 = {}, r3 = {};                               \
    if (pf_) {                                                              \
      ALOAD(r0, s_ + 1, 0) ALOAD(r1, s_ + 1, 1)                             \
      ALOAD(r2, s_ + 1, 2) ALOAD(r3, s_ + 1, 3)                             \
    }                                                                       \
    const char* bp_ = bptr + (size_t)s_ * (16 * 4096);                      \
    _Pragma("unroll") for (int kf = 0; kf < 8; ++kf) {                      \
      u16x8 bv = *(const u16x8*)(bp_ + (size_t)kf * 4096);                  \
      unsigned ko = (kgb + (unsigned)(kf * 32) + (unsigned)(lg * 16)) ^ swz;\
      u16x8 av = *(const u16x8*)((const char*)Alds[CUR] + (arb + ko));      \
      acc = __builtin_amdgcn_mfma_f32_32x32x16_bf16(                        \
          __builtin_bit_cast(bf16x8, av), __builtin_bit_cast(bf16x8, bv),   \
          acc, 0, 0, 0);                                                    \
    }                                                                       \
    if (pf_) {                                                              \
      AWRITE(NXT, r0, 0) AWRITE(NXT, r1, 1)                                 \
      AWRITE(NXT, r2, 2) AWRITE(NXT, r3, 3)                                 \
    }                                                                       \
    __syncthreads();                                                        \
  }

#pragma unroll 1
  for (int s = 0; s < 64; s += 2) {
    GSTEP(0, 1, s)
    GSTEP(1, 0, s + 1)
  }
#undef GSTEP
#undef ALOAD
#undef AWRITE

  // ---- epilogue: reduce kg halves via LDS, then coalesced store ----
  // D: col(o-local) = c*32 + lr, row(i-local) = g*8 + lg*4 + r2
  float* red = (float*)Alds;  // 32x128 f32 = 16 KB (final loop barrier passed)
  if (kg == 1) {
#pragma unroll
    for (int g = 0; g < 4; ++g) {
      const int jb = g * 8 + lg * 4;
#pragma unroll
      for (int r2 = 0; r2 < 4; ++r2)
        red[(jb + r2) * 128 + c * 32 + lr] = acc[g * 4 + r2];
    }
  }
  __syncthreads();
  if (kg == 0) {
#pragma unroll
    for (int g = 0; g < 4; ++g) {
      const int jb = g * 8 + lg * 4;
#pragma unroll
      for (int r2 = 0; r2 < 4; ++r2)
        red[(jb + r2) * 128 + c * 32 + lr] += acc[g * 4 + r2];
    }
  }
  __syncthreads();

  {
    const int row = tid >> 4;            // 0..31
    const int colseg = (tid & 15) * 8;   // 0..120
    const float nm = norm[i0 + row];
    f32x4 v0 = *(const f32x4*)(red + row * 128 + colseg);
    f32x4 v1 = *(const f32x4*)(red + row * 128 + colseg + 4);
    f32x4 b0v = *(const f32x4*)(bias + colseg);
    f32x4 b1v = *(const f32x4*)(bias + colseg + 4);
    f32x4 o0, o1;
    o0.x = nm * v0.x + b0v.x; o0.y = nm * v0.y + b0v.y;
    o0.z = nm * v0.z + b0v.z; o0.w = nm * v0.w + b0v.w;
    o1.x = nm * v1.x + b1v.x; o1.y = nm * v1.y + b1v.y;
    o1.z = nm * v1.z + b1v.z; o1.w = nm * v1.w + b1v.w;
    float* op = out + (size_t)(i0 + row) * FD + colseg;
    *(f32x4*)op = o0;
    *(f32x4*)(op + 4) = o1;
  }
}

extern "C" void kernel_launch(void* const* d_in, const int* in_sizes, int n_in,
                              void* d_out, int out_size, void* d_ws,
                              size_t ws_size, hipStream_t stream) {
  (void)in_sizes; (void)n_in; (void)out_size; (void)ws_size;
  const float* A = (const float*)d_in[0];
  const float* F = (const float*)d_in[1];
  const float* W = (const float*)d_in[2];
  const float* b = (const float*)d_in[3];
  float* out = (float*)d_out;

  float* norm = (float*)d_ws;                                     // 64 KB
  unsigned short* Bfrag = (unsigned short*)((char*)d_ws + 65536); // 4 MB

  k_rownorm<<<NN, 256, 0, stream>>>(A, norm);
  k_fwt<<<NN / 32, 256, 0, stream>>>(F, W, norm, Bfrag);
  k_gcn_gemm<<<NN / 32, 512, 0, stream>>>(A, Bfrag, norm, b, out);
}

// Round 10
// 379.682 us; speedup vs baseline: 1.2880x; 1.0251x over previous
//
#include <hip/hip_runtime.h>
#include <stdint.h>

#define NN 16384
#define FD 128

typedef float f32x4 __attribute__((ext_vector_type(4)));
typedef float f32x16 __attribute__((ext_vector_type(16)));
typedef __bf16 bf16x8 __attribute__((ext_vector_type(8)));
typedef unsigned short u16x8 __attribute__((ext_vector_type(8)));
typedef unsigned short u16x4 __attribute__((ext_vector_type(4)));

static __device__ __forceinline__ unsigned short f2bf(float x) {
  return __builtin_bit_cast(unsigned short, (__bf16)x);
}

static __device__ __forceinline__ u16x8 pack8(f32x4 a, f32x4 b) {
  u16x8 r;
  r[0] = f2bf(a.x); r[1] = f2bf(a.y); r[2] = f2bf(a.z); r[3] = f2bf(a.w);
  r[4] = f2bf(b.x); r[5] = f2bf(b.y); r[6] = f2bf(b.z); r[7] = f2bf(b.w);
  return r;
}

static __device__ __forceinline__ u16x4 pack4(f32x4 a) {
  u16x4 r;
  r[0] = f2bf(a.x); r[1] = f2bf(a.y); r[2] = f2bf(a.z); r[3] = f2bf(a.w);
  return r;
}

// ---------------- kernel 1: norm[i] = (sum_j A[i][j])^-1/2 ----------------
__global__ __launch_bounds__(256) void k_rownorm(const float* __restrict__ A,
                                                 float* __restrict__ norm) {
  const int row = blockIdx.x;
  const f32x4* ar = (const f32x4*)(A + (size_t)row * NN);
  float s = 0.f;
#pragma unroll 4
  for (int c = threadIdx.x; c < NN / 4; c += 256) {
    f32x4 v = __builtin_nontemporal_load(&ar[c]);
    s += (v.x + v.y) + (v.z + v.w);
  }
#pragma unroll
  for (int off = 32; off > 0; off >>= 1) s += __shfl_xor(s, off, 64);
  __shared__ float red[4];
  const int lane = threadIdx.x & 63, w = threadIdx.x >> 6;
  if (lane == 0) red[w] = s;
  __syncthreads();
  if (threadIdx.x == 0) {
    float d = (red[0] + red[1]) + (red[2] + red[3]);
    norm[row] = d > 0.f ? 1.f / sqrtf(d) : 0.f;
  }
}

// ------- kernel 2: Bfrag = fragment-major bf16( norm[j] * (F @ W^T)[j][o] ) -------
// Bfrag layout: entry (t = j>>4, c = o>>5, lane l, e) at byte ((t*4+c)*64 + l)*16 + e*2
// holds norm[j]*H[j][o] with o = c*32 + (l&31), j = t*16 + (l>>5)*8 + e.
__global__ __launch_bounds__(256) void k_fwt(const float* __restrict__ F,
                                             const float* __restrict__ W,
                                             const float* __restrict__ norm,
                                             unsigned short* __restrict__ Bfrag) {
  const int tid = threadIdx.x;
  const int wv = tid >> 6;
  const int l = tid & 63;
  const int lr = l & 31, lg = l >> 5;
  const int j0 = blockIdx.x * 32;

  const float* fp = F + (size_t)(j0 + lr) * FD + lg * 8;
  const float* wp = W + (size_t)(wv * 32 + lr) * FD + lg * 8;

  f32x16 acc;
#pragma unroll
  for (int i = 0; i < 16; ++i) acc[i] = 0.f;

#pragma unroll
  for (int kf = 0; kf < 8; ++kf) {
    f32x4 fa = *(const f32x4*)(fp + kf * 16);
    f32x4 fb = *(const f32x4*)(fp + kf * 16 + 4);
    f32x4 wa = *(const f32x4*)(wp + kf * 16);
    f32x4 wb = *(const f32x4*)(wp + kf * 16 + 4);
    bf16x8 av = __builtin_bit_cast(bf16x8, pack8(fa, fb));
    bf16x8 bv = __builtin_bit_cast(bf16x8, pack8(wa, wb));
    acc = __builtin_amdgcn_mfma_f32_32x32x16_bf16(av, bv, acc, 0, 0, 0);
  }

  const int jt = blockIdx.x * 2;  // j0 >> 4
#pragma unroll
  for (int g = 0; g < 4; ++g) {
    const int jb = j0 + g * 8 + lg * 4;
    u16x4 q;
#pragma unroll
    for (int r2 = 0; r2 < 4; ++r2) q[r2] = f2bf(acc[g * 4 + r2] * norm[jb + r2]);
    const size_t byteoff =
        ((size_t)((jt + (g >> 1)) * 4 + wv) * 64 + (g & 1) * 32 + lr) * 16 +
        lg * 8;
    *(u16x4*)((char*)Bfrag + byteoff) = q;
  }
}

// ---------- kernel 3: out[i][o] = norm[i] * sum_j A[i][j]*(norm[j]*H[j][o]) + b[o] ----------
// R9 structure (BM=32, 512 blocks x 512 thr, 2 blocks/CU). Single change vs R9:
// GSTEP issues B-LOADS FIRST (8 x u16x8 -> regs, pinned by sched_barrier), THEN the
// next-tile A-loads, then MFMA. vmcnt is in-order, so MFMA's counted B-waits
// (vmcnt 11..4) no longer drain the HBM A-loads; A drains only at AWRITE's vmcnt(0),
// which it had the whole MFMA phase to satisfy. MFMA+B phase now overlaps A stream.
__global__ __launch_bounds__(512, 4) void k_gcn_gemm(
    const float* __restrict__ A, const unsigned short* __restrict__ Bfrag,
    const float* __restrict__ norm, const float* __restrict__ bias,
    float* __restrict__ out) {
  __shared__ __align__(16) unsigned short Alds[2][32 * 256];  // 2 x 16 KB

  const int tid = threadIdx.x;
  const int i0 = blockIdx.x * 32;

  // A staging: wave srow (0..7), lane sl; load I covers row I*8+srow
  const int srow = tid >> 6;
  const int sl = tid & 63;
  const float* aptr = A + (size_t)(i0 + srow) * NN + (size_t)sl * 4;
  const unsigned ax0 = (unsigned)(sl * 8) ^ (unsigned)(srow << 4);
  const unsigned ax1 = (unsigned)(sl * 8) ^ (unsigned)((8 + srow) << 4);

  // fragment addressing
  const int wv = tid >> 6;          // 0..7
  const int c = wv & 3;             // col-group: o in [c*32, c*32+32)
  const int kg = wv >> 2;           // k-half within BK=256
  const int l = tid & 63;
  const int lr = l & 31, lg = l >> 5;
  const unsigned swz = (unsigned)((lr & 15) << 4);
  const unsigned arb = (unsigned)(lr * 512);
  const unsigned kgb = (unsigned)(kg * 256);  // kg*128 elements, bytes

  const char* bptr = (const char*)Bfrag + (size_t)(c * 64 + l) * 16 +
                     (size_t)kg * 8 * 4096;

  f32x16 acc;
#pragma unroll
  for (int i = 0; i < 16; ++i) acc[i] = 0.f;

#define ALOAD(RV, S, I)                                                     \
  RV = __builtin_nontemporal_load(                                          \
      (const f32x4*)(aptr + (size_t)(S) * 256 + (size_t)(I) * (8 * NN)));
#define AWRITE(BUF, RV, I)                                                  \
  *(u16x4*)((char*)Alds[BUF] +                                              \
            (((I) * 8 + srow) * 512 + (((I) & 1) ? ax1 : ax0))) = pack4(RV);

  // prologue: stage tile 0 into buffer 0
  {
    f32x4 r0, r1, r2, r3;
    ALOAD(r0, 0, 0) ALOAD(r1, 0, 1) ALOAD(r2, 0, 2) ALOAD(r3, 0, 3)
    AWRITE(0, r0, 0) AWRITE(0, r1, 1) AWRITE(0, r2, 2) AWRITE(0, r3, 3)
  }
  __syncthreads();

#define GSTEP(CUR, NXT, S)                                                  \
  {                                                                         \
    const int s_ = (S);                                                     \
    const bool pf_ = (s_ + 1) < 64;                                         \
    const char* bp_ = bptr + (size_t)s_ * (16 * 4096);                      \
    u16x8 bvs[8];                                                           \
    _Pragma("unroll") for (int kf = 0; kf < 8; ++kf)                        \
        bvs[kf] = *(const u16x8*)(bp_ + (size_t)kf * 4096);                 \
    __builtin_amdgcn_sched_barrier(0);                                      \
    f32x4 r0 = {}, r1 = {}, r2 = {}, r3 = {};                               \
    if (pf_) {                                                              \
      ALOAD(r0, s_ + 1, 0) ALOAD(r1, s_ + 1, 1)                             \
      ALOAD(r2, s_ + 1, 2) ALOAD(r3, s_ + 1, 3)                             \
    }                                                                       \
    _Pragma("unroll") for (int kf = 0; kf < 8; ++kf) {                      \
      unsigned ko = (kgb + (unsigned)(kf * 32) + (unsigned)(lg * 16)) ^ swz;\
      u16x8 av = *(const u16x8*)((const char*)Alds[CUR] + (arb + ko));      \
      acc = __builtin_amdgcn_mfma_f32_32x32x16_bf16(                        \
          __builtin_bit_cast(bf16x8, av), __builtin_bit_cast(bf16x8, bvs[kf]), \
          acc, 0, 0, 0);                                                    \
    }                                                                       \
    if (pf_) {                                                              \
      AWRITE(NXT, r0, 0) AWRITE(NXT, r1, 1)                                 \
      AWRITE(NXT, r2, 2) AWRITE(NXT, r3, 3)                                 \
    }                                                                       \
    __syncthreads();                                                        \
  }

#pragma unroll 1
  for (int s = 0; s < 64; s += 2) {
    GSTEP(0, 1, s)
    GSTEP(1, 0, s + 1)
  }
#undef GSTEP
#undef ALOAD
#undef AWRITE

  // ---- epilogue: reduce kg halves via LDS, then coalesced store ----
  // D: col(o-local) = c*32 + lr, row(i-local) = g*8 + lg*4 + r2
  float* red = (float*)Alds;  // 32x128 f32 = 16 KB (final loop barrier passed)
  if (kg == 1) {
#pragma unroll
    for (int g = 0; g < 4; ++g) {
      const int jb = g * 8 + lg * 4;
#pragma unroll
      for (int r2 = 0; r2 < 4; ++r2)
        red[(jb + r2) * 128 + c * 32 + lr] = acc[g * 4 + r2];
    }
  }
  __syncthreads();
  if (kg == 0) {
#pragma unroll
    for (int g = 0; g < 4; ++g) {
      const int jb = g * 8 + lg * 4;
#pragma unroll
      for (int r2 = 0; r2 < 4; ++r2)
        red[(jb + r2) * 128 + c * 32 + lr] += acc[g * 4 + r2];
    }
  }
  __syncthreads();

  {
    const int row = tid >> 4;            // 0..31
    const int colseg = (tid & 15) * 8;   // 0..120
    const float nm = norm[i0 + row];
    f32x4 v0 = *(const f32x4*)(red + row * 128 + colseg);
    f32x4 v1 = *(const f32x4*)(red + row * 128 + colseg + 4);
    f32x4 b0v = *(const f32x4*)(bias + colseg);
    f32x4 b1v = *(const f32x4*)(bias + colseg + 4);
    f32x4 o0, o1;
    o0.x = nm * v0.x + b0v.x; o0.y = nm * v0.y + b0v.y;
    o0.z = nm * v0.z + b0v.z; o0.w = nm * v0.w + b0v.w;
    o1.x = nm * v1.x + b1v.x; o1.y = nm * v1.y + b1v.y;
    o1.z = nm * v1.z + b1v.z; o1.w = nm * v1.w + b1v.w;
    float* op = out + (size_t)(i0 + row) * FD + colseg;
    *(f32x4*)op = o0;
    *(f32x4*)(op + 4) = o1;
  }
}

extern "C" void kernel_launch(void* const* d_in, const int* in_sizes, int n_in,
                              void* d_out, int out_size, void* d_ws,
                              size_t ws_size, hipStream_t stream) {
  (void)in_sizes; (void)n_in; (void)out_size; (void)ws_size;
  const float* A = (const float*)d_in[0];
  const float* F = (const float*)d_in[1];
  const float* W = (const float*)d_in[2];
  const float* b = (const float*)d_in[3];
  float* out = (float*)d_out;

  float* norm = (float*)d_ws;                                     // 64 KB
  unsigned short* Bfrag = (unsigned short*)((char*)d_ws + 65536); // 4 MB

  k_rownorm<<<NN, 256, 0, stream>>>(A, norm);
  k_fwt<<<NN / 32, 256, 0, stream>>>(F, W, norm, Bfrag);
  k_gcn_gemm<<<NN / 32, 512, 0, stream>>>(A, Bfrag, norm, b, out);
}